// Round 10
// baseline (176.785 us; speedup 1.0000x reference)
//
#include <hip/hip_runtime.h>
#include <hip/hip_bf16.h>

// EdgePredictor: out[e] = relu(concat(X[row], X[col]) @ W1 + b1) @ W2 + b2
// Precompute per-node AB[n][256] = {X[n]@W1[:128,:] | X[n]@W1[128:,:]} in f16.
// Per edge: out = relu(A[row] + B[col] + b1) @ W2 + b2.
//
// R10 (single-variable: gemm_ab only): R9 prefetch was +3us only — the
// serializer is the barrier-phased structure itself (4x vmcnt(0) barrier
// drains per tile; waves load in lockstep bursts). gemm v7 is BARRIER-FREE:
// each wave independently owns 32 nodes x 128 cols (acc[2][8]); X goes
// global->reg->cvt->MFMA (no staging LDS); epilogue coalesces through a
// WAVE-PRIVATE LDS tile (same-wave ds_write/ds_read needs only lgkmcnt,
// no s_barrier). Zero __syncthreads. Edge floor (7 variants ~49us) and
// prep unchanged.

#define EMBED 128

typedef _Float16 half8 __attribute__((ext_vector_type(8)));
typedef _Float16 half4 __attribute__((ext_vector_type(4)));
typedef float floatx4 __attribute__((ext_vector_type(4)));

// --- Kernel 0: fused prep.
// Blocks 0..127: transpose+convert W1 (256x128 f32) -> WT (256x128 f16),
//   WT[j][k] = Wcat[k][j] (Wcat = [W1 top | W1 bottom] per concat split).
// Block 128: idx-mode ballot detect; W2PT[16][128] f16; b1f[128] f16.
__global__ __launch_bounds__(256) void prep(
    const float* __restrict__ W1, const float* __restrict__ W2,
    const float* __restrict__ b1, const int* __restrict__ idx,
    _Float16* __restrict__ WT, _Float16* __restrict__ W2PT,
    _Float16* __restrict__ b1f, int* __restrict__ flag) {
    if (blockIdx.x < 128) {
        __shared__ float lds[16][17];
        const int ty = threadIdx.x >> 4, tx = threadIdx.x & 15;
        const int r0 = (blockIdx.x >> 3) * 16;   // source W1 row tile
        const int c0 = (blockIdx.x & 7) * 16;    // source W1 col tile
        lds[ty][tx] = W1[(r0 + ty) * 128 + c0 + tx];
        __syncthreads();
        const int jbase = c0 + (r0 >= 128 ? 128 : 0);
        const int kbase = r0 & 127;
        WT[(size_t)(jbase + ty) * 128 + kbase + tx] = (_Float16)lds[tx][ty];
    } else {
        const int t = threadIdx.x;
        if (t < 64) {  // int64 layout iff first 64 high words are all zero
            const int hw = idx[2 * t + 1];
            const unsigned long long m = __ballot(hw != 0);
            if (t == 0) *flag = (m == 0ull) ? 1 : 0;
        }
        if (t < 128) b1f[t] = (_Float16)b1[t];
        for (int i = t; i < 2048; i += 256) {  // W2PT[n][k] = n<2 ? W2[k][n] : 0
            const int n = i >> 7, k = i & 127;
            W2PT[i] = (n < 2) ? (_Float16)W2[k * 2 + n] : (_Float16)0.f;
        }
    }
}

// --- Kernel 1: AB = [X | X] @ Wcat, barrier-free. Block = 4 independent
// waves; wave wv: nodes base + (wv>>1)*32 .. +32, cols (wv&1)*128 .. +128.
// Operand-swapped MFMA (A=WT-frag, B=X-frag): D[col=lane&15 -> node]
// [row=quad*4+r -> col j]. Epilogue via wave-private padded LDS tile.
__global__ __launch_bounds__(256) void gemm_ab(
    const float* __restrict__ X, const _Float16* __restrict__ WT,
    _Float16* __restrict__ AB, int n_nodes) {
    __shared__ _Float16 outs[4][32 * 136];  // 8704 B per wave, 34.8 KB total
    const int t = threadIdx.x;
    const int wv = t >> 6, lane = t & 63, lm = lane & 15, quad = lane >> 4;
    const int base    = blockIdx.x * 64 + (wv >> 1) * 32;  // 32-node group
    const int colbase = (wv & 1) * 128;                    // col half

    // X rows this lane feeds as B-operand: n = lm (group 0), 16+lm (group 1).
    int r0 = base + lm;      if (r0 > n_nodes - 1) r0 = n_nodes - 1;
    int r1 = base + 16 + lm; if (r1 > n_nodes - 1) r1 = n_nodes - 1;
    const float* x0 = X + (size_t)r0 * EMBED;
    const float* x1 = X + (size_t)r1 * EMBED;
    const _Float16* wtp = WT + (size_t)(colbase + lm) * EMBED;  // + jf*16*128

    floatx4 acc[2][8];  // [node group][jf col tile]
#pragma unroll
    for (int a = 0; a < 2; ++a)
#pragma unroll
        for (int b = 0; b < 8; ++b)
            acc[a][b] = (floatx4){0.f, 0.f, 0.f, 0.f};

#pragma unroll
    for (int ks = 0; ks < 4; ++ks) {
        const int k0 = ks * 32 + quad * 8;
        // B-frags: X[row][k0..k0+8] -> f16 (direct, no staging LDS).
        const float4 a0 = *(const float4*)(x0 + k0);
        const float4 a1 = *(const float4*)(x0 + k0 + 4);
        const float4 c0 = *(const float4*)(x1 + k0);
        const float4 c1 = *(const float4*)(x1 + k0 + 4);
        half8 xf0, xf1;
        xf0[0] = (_Float16)a0.x; xf0[1] = (_Float16)a0.y;
        xf0[2] = (_Float16)a0.z; xf0[3] = (_Float16)a0.w;
        xf0[4] = (_Float16)a1.x; xf0[5] = (_Float16)a1.y;
        xf0[6] = (_Float16)a1.z; xf0[7] = (_Float16)a1.w;
        xf1[0] = (_Float16)c0.x; xf1[1] = (_Float16)c0.y;
        xf1[2] = (_Float16)c0.z; xf1[3] = (_Float16)c0.w;
        xf1[4] = (_Float16)c1.x; xf1[5] = (_Float16)c1.y;
        xf1[6] = (_Float16)c1.z; xf1[7] = (_Float16)c1.w;
#pragma unroll
        for (int jf = 0; jf < 8; ++jf) {
            // A-frag: WT[colbase + jf*16 + lm][k0..k0+8], 16B L2 hit.
            const half8 wf = *(const half8*)(wtp + (size_t)jf * 16 * EMBED + k0);
            acc[0][jf] = __builtin_amdgcn_mfma_f32_16x16x32_f16(wf, xf0, acc[0][jf], 0, 0, 0);
            acc[1][jf] = __builtin_amdgcn_mfma_f32_16x16x32_f16(wf, xf1, acc[1][jf], 0, 0, 0);
        }
    }

    // Epilogue (wave-private; no barrier). Pack D into outs[wv]:
    // node-local row = mf*16+lm, local col = jf*16 + quad*4 + r, stride 136.
    _Float16* o = outs[wv];
#pragma unroll
    for (int mf = 0; mf < 2; ++mf) {
#pragma unroll
        for (int jf = 0; jf < 8; ++jf) {
            half4 h;
#pragma unroll
            for (int r = 0; r < 4; ++r) h[r] = (_Float16)acc[mf][jf][r];
            *(half4*)(o + (mf * 16 + lm) * 136 + jf * 16 + quad * 4) = h;
        }
    }
    // Same-wave ds_write->ds_read: compiler inserts lgkmcnt wait, no s_barrier.
    // Flush: 32 nodes x 256 B (this wave's col half), 4 nodes per instr.
#pragma unroll
    for (int i = 0; i < 8; ++i) {
        const int nl = i * 4 + (lane >> 4);  // local node 0..31
        const int gnode = base + nl;
        const half8 v = *(const half8*)(o + nl * 136 + lm * 8);
        if (gnode < n_nodes)
            *(half8*)(AB + (size_t)gnode * 256 + colbase + lm * 8) = v;
    }
}

// --- Kernel 2: per-edge MLP, 32 edges/wave (2 MFMA groups), all gathers
// issued before compute. Lane l serves edges ebase+(l&15) and ebase+16+(l&15);
// gathers land directly in MFMA A-layout (A[m=lane&15][k=quad*8+j]).
__global__ __launch_bounds__(256) void edge_mlp(
    const _Float16* __restrict__ AB, const int* __restrict__ eidx,
    const int* __restrict__ flag, const _Float16* __restrict__ b1f,
    const _Float16* __restrict__ W2PT, const float* __restrict__ b2,
    float* __restrict__ out, int n_edges) {
    const int lane = threadIdx.x & 63, lm = lane & 15, quad = lane >> 4;
    const int ebase = (blockIdx.x * 4 + (threadIdx.x >> 6)) * 32;
    if (ebase >= n_edges) return;

    const int mode = *flag;  // wave-uniform
    int e0 = ebase + lm, e1 = ebase + 16 + lm;
    if (e0 > n_edges - 1) e0 = n_edges - 1;  // tail clamp; stores guarded
    if (e1 > n_edges - 1) e1 = n_edges - 1;
    int row0, col0, row1, col1;
    if (mode) {  // int64 layout: low word at int32 index 2*k
        row0 = eidx[2 * (size_t)e0];
        col0 = eidx[2 * ((size_t)n_edges + e0)];
        row1 = eidx[2 * (size_t)e1];
        col1 = eidx[2 * ((size_t)n_edges + e1)];
    } else {
        row0 = eidx[e0];
        col0 = eidx[(size_t)n_edges + e0];
        row1 = eidx[e1];
        col1 = eidx[(size_t)n_edges + e1];
    }

    const _Float16* a0p = AB + (size_t)row0 * 256;
    const _Float16* b0p = AB + (size_t)col0 * 256 + 128;
    const _Float16* a1p = AB + (size_t)row1 * 256;
    const _Float16* b1p = AB + (size_t)col1 * 256 + 128;

    // Issue all 16 gathers up front (each b128: 16 edges x one 64B line).
    half8 a0[4], b0[4], a1[4], b1[4];
#pragma unroll
    for (int ks = 0; ks < 4; ++ks) {
        const int k0 = ks * 32 + quad * 8;
        a0[ks] = *(const half8*)(a0p + k0);
        b0[ks] = *(const half8*)(b0p + k0);
        a1[ks] = *(const half8*)(a1p + k0);
        b1[ks] = *(const half8*)(b1p + k0);
    }

    floatx4 acc0 = (floatx4){0.f, 0.f, 0.f, 0.f};
    floatx4 acc1 = (floatx4){0.f, 0.f, 0.f, 0.f};
#pragma unroll
    for (int ks = 0; ks < 4; ++ks) {
        const int k0 = ks * 32 + quad * 8;
        const half8 bi = *(const half8*)(b1f + k0);          // wave-uniform
        const half8 wv = *(const half8*)(W2PT + lm * 128 + k0);
        half8 h0 = a0[ks] + b0[ks] + bi;
        half8 h1 = a1[ks] + b1[ks] + bi;
#pragma unroll
        for (int j = 0; j < 8; ++j) {
            h0[j] = h0[j] > (_Float16)0.f ? h0[j] : (_Float16)0.f;
            h1[j] = h1[j] > (_Float16)0.f ? h1[j] : (_Float16)0.f;
        }
        acc0 = __builtin_amdgcn_mfma_f32_16x16x32_f16(h0, wv, acc0, 0, 0, 0);
        acc1 = __builtin_amdgcn_mfma_f32_16x16x32_f16(h1, wv, acc1, 0, 0, 0);
    }

    if (lm < 2) {
        const float b2v = b2[lm];
#pragma unroll
        for (int r = 0; r < 4; ++r) {
            const int ed0 = ebase + quad * 4 + r;
            const int ed1 = ebase + 16 + quad * 4 + r;
            if (ed0 < n_edges) out[(size_t)ed0 * 2 + lm] = acc0[r] + b2v;
            if (ed1 < n_edges) out[(size_t)ed1 * 2 + lm] = acc1[r] + b2v;
        }
    }
}

extern "C" void kernel_launch(void* const* d_in, const int* in_sizes, int n_in,
                              void* d_out, int out_size, void* d_ws, size_t ws_size,
                              hipStream_t stream) {
    const float* X   = (const float*)d_in[0];
    const int*   idx = (const int*)d_in[1];
    const float* W1  = (const float*)d_in[2];
    const float* b1  = (const float*)d_in[3];
    const float* W2  = (const float*)d_in[4];
    const float* b2  = (const float*)d_in[5];
    float* out = (float*)d_out;

    const int n_nodes = in_sizes[0] / EMBED;   // 100000
    const int n_edges = in_sizes[1] / 2;       // 500000

    // ws: flag @0 | AB @256 (n_nodes*256*2 B) | WT (64KB) | W2PT (4KB) | b1f (256B)
    char* ws = (char*)d_ws;
    int*      flag = (int*)ws;
    _Float16* AB   = (_Float16*)(ws + 256);
    _Float16* WT   = (_Float16*)(ws + 256 + (size_t)n_nodes * 512);
    _Float16* W2PT = WT + 256 * 128;
    _Float16* b1f  = W2PT + 16 * 128;

    prep<<<129, 256, 0, stream>>>(W1, W2, b1, idx, WT, W2PT, b1f, flag);
    gemm_ab<<<(n_nodes + 63) / 64, 256, 0, stream>>>(X, WT, AB, n_nodes);
    edge_mlp<<<(n_edges + 127) / 128, 256, 0, stream>>>(
        AB, idx, flag, b1f, W2PT, b2, out, n_edges);
}

// Round 11
// 155.384 us; speedup vs baseline: 1.1377x; 1.1377x over previous
//
#include <hip/hip_runtime.h>
#include <hip/hip_bf16.h>

// EdgePredictor: out[e] = relu(concat(X[row], X[col]) @ W1 + b1) @ W2 + b2
// Precompute per-node AB[n][256] = {X[n]@W1[:128,:] | X[n]@W1[128:,:]} in f16.
// Per edge: out = relu(A[row] + B[col] + b1) @ W2 + b2.
//
// R11: revert gemm to R9 (best measured: gemm ~29.5us by ledger closure —
// R10's barrier-free variant directly measured 53us and exposed counters:
// FETCH 25.6MB / WRITE 50MB, all pipes idle). Ledger across 10 rounds:
// OH ~71us (invariant) + edge ~49 (pinned, 7 variants) + gemm ~29 + prep ~3.
// Both heavy kernels run at the same measured ~2.6 TB/s irregular-traffic
// rate (edge 128MB/49us, gemm 77MB/29.5us). Single probe this round:
// nontemporal AB stores (nt: skip L2 allocate on the 50MB write stream;
// edge's hit rate is intra-edge reuse, invariant to gemm warmth).

#define EMBED 128

typedef _Float16 half8 __attribute__((ext_vector_type(8)));
typedef _Float16 half4 __attribute__((ext_vector_type(4)));
typedef float floatx4 __attribute__((ext_vector_type(4)));

// --- Kernel 0: fused prep.
// Blocks 0..127: transpose+convert W1 (256x128 f32) -> WT (256x128 f16),
//   WT[j][k] = Wcat[k][j] (Wcat = [W1 top | W1 bottom] per concat split).
// Block 128: idx-mode ballot detect; W2PT[16][128] f16; b1f[128] f16.
__global__ __launch_bounds__(256) void prep(
    const float* __restrict__ W1, const float* __restrict__ W2,
    const float* __restrict__ b1, const int* __restrict__ idx,
    _Float16* __restrict__ WT, _Float16* __restrict__ W2PT,
    _Float16* __restrict__ b1f, int* __restrict__ flag) {
    if (blockIdx.x < 128) {
        __shared__ float lds[16][17];
        const int ty = threadIdx.x >> 4, tx = threadIdx.x & 15;
        const int r0 = (blockIdx.x >> 3) * 16;   // source W1 row tile
        const int c0 = (blockIdx.x & 7) * 16;    // source W1 col tile
        lds[ty][tx] = W1[(r0 + ty) * 128 + c0 + tx];
        __syncthreads();
        const int jbase = c0 + (r0 >= 128 ? 128 : 0);
        const int kbase = r0 & 127;
        WT[(size_t)(jbase + ty) * 128 + kbase + tx] = (_Float16)lds[tx][ty];
    } else {
        const int t = threadIdx.x;
        if (t < 64) {  // int64 layout iff first 64 high words are all zero
            const int hw = idx[2 * t + 1];
            const unsigned long long m = __ballot(hw != 0);
            if (t == 0) *flag = (m == 0ull) ? 1 : 0;
        }
        if (t < 128) b1f[t] = (_Float16)b1[t];
        for (int i = t; i < 2048; i += 256) {  // W2PT[n][k] = n<2 ? W2[k][n] : 0
            const int n = i >> 7, k = i & 127;
            W2PT[i] = (n < 2) ? (_Float16)W2[k * 2 + n] : (_Float16)0.f;
        }
    }
}

// --- Kernel 1: AB = [X | X] @ Wcat via f16 MFMA, operand-swapped
// (A-operand = W-frag so D rows are output cols). Grid-stride, 2 tiles per
// block; next tile's X loads prefetched into registers during compute.
// xs (stage, stride 136) and outs (epilogue, stride 264) share 34KB LDS.
// AB flush uses nontemporal stores (nt).
__global__ __launch_bounds__(256) void gemm_ab(
    const float* __restrict__ X, const _Float16* __restrict__ WT,
    _Float16* __restrict__ AB, int n_nodes, int n_tiles) {
    __shared__ _Float16 sh[64 * 264];  // 33792 B union: xs(17408) / outs(33792)
    _Float16* xs   = sh;               // stride 136
    _Float16* outs = sh;               // stride 264
    const int t = threadIdx.x;
    const int w = t >> 6, lane = t & 63, lm = lane & 15, quad = lane >> 4;

    // Per-thread stage coordinates (fixed across tiles).
    int srow[8], scol[8];
#pragma unroll
    for (int i = 0; i < 8; ++i) {
        const int flat = i * 1024 + t * 4;
        srow[i] = flat >> 7;
        scol[i] = flat & 127;
    }

    int T = blockIdx.x;
    float4 pf[8];
    if (T < n_tiles) {  // prefetch first tile
#pragma unroll
        for (int i = 0; i < 8; ++i) {
            int node = T * 64 + srow[i];
            if (node > n_nodes - 1) node = n_nodes - 1;  // clamp; never stored
            pf[i] = *(const float4*)(X + (size_t)node * EMBED + scol[i]);
        }
    }

    for (; T < n_tiles; T += gridDim.x) {
        const int mblk = T * 64;

        // Stage: spill prefetched registers to LDS (convert f32->f16 once).
#pragma unroll
        for (int i = 0; i < 8; ++i) {
            half4 h;
            h[0] = (_Float16)pf[i].x; h[1] = (_Float16)pf[i].y;
            h[2] = (_Float16)pf[i].z; h[3] = (_Float16)pf[i].w;
            *(half4*)(xs + srow[i] * 136 + scol[i]) = h;
        }
        __syncthreads();  // S1: stage visible

        // Prefetch next tile NOW — loads overlap this tile's MFMA+epilogue.
        const int Tn = T + gridDim.x;
        if (Tn < n_tiles) {
#pragma unroll
            for (int i = 0; i < 8; ++i) {
                int node = Tn * 64 + srow[i];
                if (node > n_nodes - 1) node = n_nodes - 1;
                pf[i] = *(const float4*)(X + (size_t)node * EMBED + scol[i]);
            }
        }

        floatx4 acc[4][4];  // [mf: node tile][jf: col tile]
#pragma unroll
        for (int a = 0; a < 4; ++a)
#pragma unroll
            for (int b = 0; b < 4; ++b)
                acc[a][b] = (floatx4){0.f, 0.f, 0.f, 0.f};

#pragma unroll
        for (int ks = 0; ks < 4; ++ks) {
            const int k0 = ks * 32 + quad * 8;
            half8 xf[4];  // B-operand: B[k][n=lane&15] = Xf16[node mf*16+lm][k]
#pragma unroll
            for (int mf = 0; mf < 4; ++mf)
                xf[mf] = *(const half8*)(xs + (mf * 16 + lm) * 136 + k0);
#pragma unroll
            for (int jf = 0; jf < 4; ++jf) {
                const int j = w * 64 + jf * 16 + lm;  // A-op: WT row = out col
                const half8 wf = *(const half8*)(WT + (size_t)j * EMBED + k0);
#pragma unroll
                for (int mf = 0; mf < 4; ++mf)
                    acc[mf][jf] = __builtin_amdgcn_mfma_f32_16x16x32_f16(wf, xf[mf], acc[mf][jf], 0, 0, 0);
            }
        }
        __syncthreads();  // S2: xs reads done before outs overwrites union

        // Pack D into LDS out tile: node-major [local node][j], stride 264.
        // D: col(lane&15) = node within mf-tile, row(quad*4+r) = output col j.
#pragma unroll
        for (int mf = 0; mf < 4; ++mf) {
#pragma unroll
            for (int jf = 0; jf < 4; ++jf) {
                half4 h;
#pragma unroll
                for (int r = 0; r < 4; ++r) h[r] = (_Float16)acc[mf][jf][r];
                *(half4*)(outs + (mf * 16 + lm) * 264 + w * 64 + jf * 16 + quad * 4) = h;
            }
        }
        __syncthreads();  // S3: outs visible

        // Coalesced nontemporal store: 64 nodes x 512 B contiguous in AB.
#pragma unroll
        for (int i = 0; i < 8; ++i) {
            const int idx8 = i * 256 + t;         // half8 index in 64x256 tile
            const int node = idx8 >> 5, jj = idx8 & 31;
            if (mblk + node < n_nodes) {
                const half8 v = *(const half8*)(outs + node * 264 + jj * 8);
                __builtin_nontemporal_store(
                    v, (half8*)(AB + (size_t)(mblk + node) * 256 + jj * 8));
            }
        }
        __syncthreads();  // S4: outs reads done before next tile's stage
    }
}

// --- Kernel 2: per-edge MLP, 32 edges/wave (2 MFMA groups), all gathers
// issued before compute. Lane l serves edges ebase+(l&15) and ebase+16+(l&15);
// gathers land directly in MFMA A-layout (A[m=lane&15][k=quad*8+j]).
__global__ __launch_bounds__(256) void edge_mlp(
    const _Float16* __restrict__ AB, const int* __restrict__ eidx,
    const int* __restrict__ flag, const _Float16* __restrict__ b1f,
    const _Float16* __restrict__ W2PT, const float* __restrict__ b2,
    float* __restrict__ out, int n_edges) {
    const int lane = threadIdx.x & 63, lm = lane & 15, quad = lane >> 4;
    const int ebase = (blockIdx.x * 4 + (threadIdx.x >> 6)) * 32;
    if (ebase >= n_edges) return;

    const int mode = *flag;  // wave-uniform
    int e0 = ebase + lm, e1 = ebase + 16 + lm;
    if (e0 > n_edges - 1) e0 = n_edges - 1;  // tail clamp; stores guarded
    if (e1 > n_edges - 1) e1 = n_edges - 1;
    int row0, col0, row1, col1;
    if (mode) {  // int64 layout: low word at int32 index 2*k
        row0 = eidx[2 * (size_t)e0];
        col0 = eidx[2 * ((size_t)n_edges + e0)];
        row1 = eidx[2 * (size_t)e1];
        col1 = eidx[2 * ((size_t)n_edges + e1)];
    } else {
        row0 = eidx[e0];
        col0 = eidx[(size_t)n_edges + e0];
        row1 = eidx[e1];
        col1 = eidx[(size_t)n_edges + e1];
    }

    const _Float16* a0p = AB + (size_t)row0 * 256;
    const _Float16* b0p = AB + (size_t)col0 * 256 + 128;
    const _Float16* a1p = AB + (size_t)row1 * 256;
    const _Float16* b1p = AB + (size_t)col1 * 256 + 128;

    // Issue all 16 gathers up front (each b128: 16 edges x one 64B line).
    half8 a0[4], b0[4], a1[4], b1[4];
#pragma unroll
    for (int ks = 0; ks < 4; ++ks) {
        const int k0 = ks * 32 + quad * 8;
        a0[ks] = *(const half8*)(a0p + k0);
        b0[ks] = *(const half8*)(b0p + k0);
        a1[ks] = *(const half8*)(a1p + k0);
        b1[ks] = *(const half8*)(b1p + k0);
    }

    floatx4 acc0 = (floatx4){0.f, 0.f, 0.f, 0.f};
    floatx4 acc1 = (floatx4){0.f, 0.f, 0.f, 0.f};
#pragma unroll
    for (int ks = 0; ks < 4; ++ks) {
        const int k0 = ks * 32 + quad * 8;
        const half8 bi = *(const half8*)(b1f + k0);          // wave-uniform
        const half8 wv = *(const half8*)(W2PT + lm * 128 + k0);
        half8 h0 = a0[ks] + b0[ks] + bi;
        half8 h1 = a1[ks] + b1[ks] + bi;
#pragma unroll
        for (int j = 0; j < 8; ++j) {
            h0[j] = h0[j] > (_Float16)0.f ? h0[j] : (_Float16)0.f;
            h1[j] = h1[j] > (_Float16)0.f ? h1[j] : (_Float16)0.f;
        }
        acc0 = __builtin_amdgcn_mfma_f32_16x16x32_f16(h0, wv, acc0, 0, 0, 0);
        acc1 = __builtin_amdgcn_mfma_f32_16x16x32_f16(h1, wv, acc1, 0, 0, 0);
    }

    if (lm < 2) {
        const float b2v = b2[lm];
#pragma unroll
        for (int r = 0; r < 4; ++r) {
            const int ed0 = ebase + quad * 4 + r;
            const int ed1 = ebase + 16 + quad * 4 + r;
            if (ed0 < n_edges) out[(size_t)ed0 * 2 + lm] = acc0[r] + b2v;
            if (ed1 < n_edges) out[(size_t)ed1 * 2 + lm] = acc1[r] + b2v;
        }
    }
}

extern "C" void kernel_launch(void* const* d_in, const int* in_sizes, int n_in,
                              void* d_out, int out_size, void* d_ws, size_t ws_size,
                              hipStream_t stream) {
    const float* X   = (const float*)d_in[0];
    const int*   idx = (const int*)d_in[1];
    const float* W1  = (const float*)d_in[2];
    const float* b1  = (const float*)d_in[3];
    const float* W2  = (const float*)d_in[4];
    const float* b2  = (const float*)d_in[5];
    float* out = (float*)d_out;

    const int n_nodes = in_sizes[0] / EMBED;   // 100000
    const int n_edges = in_sizes[1] / 2;       // 500000

    // ws: flag @0 | AB @256 (n_nodes*256*2 B) | WT (64KB) | W2PT (4KB) | b1f (256B)
    char* ws = (char*)d_ws;
    int*      flag = (int*)ws;
    _Float16* AB   = (_Float16*)(ws + 256);
    _Float16* WT   = (_Float16*)(ws + 256 + (size_t)n_nodes * 512);
    _Float16* W2PT = WT + 256 * 128;
    _Float16* b1f  = W2PT + 16 * 128;

    const int n_tiles = (n_nodes + 63) / 64;   // 1563

    prep<<<129, 256, 0, stream>>>(W1, W2, b1, idx, WT, W2PT, b1f, flag);
    gemm_ab<<<782, 256, 0, stream>>>(X, WT, AB, n_nodes, n_tiles);
    edge_mlp<<<(n_edges + 127) / 128, 256, 0, stream>>>(
        AB, idx, flag, b1f, W2PT, b2, out, n_edges);
}